// Round 2
// baseline (1115.243 us; speedup 1.0000x reference)
//
#include <hip/hip_runtime.h>
#include <math.h>
#include <limits.h>

#define E_N   256
#define K_TOP 8
#define BM    64
#define BK    32
#define NT    512
#define SCALE_F 2.5f

#define AS_PITCH (BM + 4)
#define BS_PITCH (E_N + 1)

__device__ __forceinline__ float sqrtsoftplus(float x) {
    const float sp = (x > 20.f) ? x : log1pf(expf(x));
    return sqrtf(sp);
}

// grid = N/BM blocks (256), NT=512 threads. Each block: 64 rows x 256 experts.
// GEMM accumulates in fp64 (v_fma_f64) so logits match the numpy reference to
// ~1e-13 relative -> top-8 selection order is exact (near-tie-proof).
__global__ __launch_bounds__(NT, 2) void router_fused(
    const float* __restrict__ hidden,
    const float* __restrict__ gatew,
    const float* __restrict__ ebias,
    float* __restrict__ probs,
    float* __restrict__ rmap,
    int N, int D)
{
    __shared__ float As[BK][AS_PITCH];
    __shared__ float Bs[BK][BS_PITCH];
    __shared__ float biasS[E_N];
    __shared__ int   biasNZ;
    __shared__ int   selE[BM][K_TOP];
    __shared__ float selLf[BM][K_TOP];
    __shared__ float selW[BM][K_TOP];
    __shared__ float invD[BM];

    const int t  = threadIdx.x;
    const int tx = t & 31;        // expert lane: e = tx + 32*j (conflict-free Bs)
    const int ty = t >> 5;        // 0..15 ; rows r0..r0+3
    const int r0 = ty * 4;
    const long n0 = (long)blockIdx.x * BM;

    double acc[4][8];
    #pragma unroll
    for (int i = 0; i < 4; ++i)
        #pragma unroll
        for (int j = 0; j < 8; ++j) acc[i][j] = 0.0;

    // loader mapping: A: 64 rows x 32 k (1 float4/thread); B: 256 x 32 (4 float4/thread)
    const int lr = t >> 3;            // 0..63
    const int lk = (t & 7) * 4;       // 0,4,...,28
    const float* aP  = hidden + (n0 + lr) * (long)D + lk;
    const float* bP0 = gatew + (long)(lr +   0) * D + lk;
    const float* bP1 = gatew + (long)(lr +  64) * D + lk;
    const float* bP2 = gatew + (long)(lr + 128) * D + lk;
    const float* bP3 = gatew + (long)(lr + 192) * D + lk;

    float4 aReg = *(const float4*)(aP);
    float4 bReg[4];
    bReg[0] = *(const float4*)(bP0);
    bReg[1] = *(const float4*)(bP1);
    bReg[2] = *(const float4*)(bP2);
    bReg[3] = *(const float4*)(bP3);

    for (int k0 = 0; k0 < D; k0 += BK) {
        __syncthreads();
        {   // stage regs -> LDS (transposed: [k][row/expert])
            const float* av = (const float*)&aReg;
            #pragma unroll
            for (int q = 0; q < 4; ++q) As[lk + q][lr] = av[q];
            #pragma unroll
            for (int p = 0; p < 4; ++p) {
                const int e = lr + 64 * p;
                Bs[lk + 0][e] = bReg[p].x;
                Bs[lk + 1][e] = bReg[p].y;
                Bs[lk + 2][e] = bReg[p].z;
                Bs[lk + 3][e] = bReg[p].w;
            }
        }
        __syncthreads();
        const int kn = k0 + BK;
        if (kn < D) {   // prefetch next tile while computing this one
            aReg    = *(const float4*)(aP  + kn);
            bReg[0] = *(const float4*)(bP0 + kn);
            bReg[1] = *(const float4*)(bP1 + kn);
            bReg[2] = *(const float4*)(bP2 + kn);
            bReg[3] = *(const float4*)(bP3 + kn);
        }
        #pragma unroll 4
        for (int k = 0; k < BK; ++k) {
            const float4 av = *(const float4*)&As[k][r0];
            const double ad[4] = {(double)av.x, (double)av.y, (double)av.z, (double)av.w};
            double bd[8];
            #pragma unroll
            for (int j = 0; j < 8; ++j) bd[j] = (double)Bs[k][tx + 32 * j];
            #pragma unroll
            for (int i = 0; i < 4; ++i)
                #pragma unroll
                for (int j = 0; j < 8; ++j)
                    acc[i][j] = fma(ad[i], bd[j], acc[i][j]);
        }
    }

    // ---- bias load + all-zero check (bias==0 => selection order == logit order) ----
    if (t == 0) biasNZ = 0;
    __syncthreads();
    if (t < E_N) {
        const float b = ebias[t];
        biasS[t] = b;
        if (b != 0.f) atomicOr(&biasNZ, 1);
    }
    __syncthreads();
    const bool bz = (biasNZ == 0);

    // ---- per-row top-8 via half-wave (32-lane) shuffle extraction ----
    #pragma unroll
    for (int i = 0; i < 4; ++i) {
        const int r = r0 + i;
        double key[8]; float lf[8];
        #pragma unroll
        for (int j = 0; j < 8; ++j) {
            lf[j] = (float)acc[i][j];
            key[j] = bz ? acc[i][j]
                        : (double)(sqrtsoftplus(lf[j]) + biasS[tx + 32 * j]);
        }
        unsigned alive = 0xFFu;
        for (int k = 0; k < K_TOP; ++k) {
            double bv = -(double)INFINITY; float bf = 0.f; int be = INT_MAX;
            #pragma unroll
            for (int j = 0; j < 8; ++j) {   // ascending j => lowest expert wins ties
                if ((alive >> j) & 1u) {
                    if (key[j] > bv) { bv = key[j]; bf = lf[j]; be = tx + 32 * j; }
                }
            }
            #pragma unroll
            for (int m = 16; m >= 1; m >>= 1) {
                const double ov = __shfl_xor(bv, m, 32);
                const float  of = __shfl_xor(bf, m, 32);
                const int    oe = __shfl_xor(be, m, 32);
                if (ov > bv || (ov == bv && oe < be)) { bv = ov; bf = of; be = oe; }
            }
            if (tx == k) { selE[r][k] = be; selLf[r][k] = bf; }
            if ((be & 31) == tx) alive &= ~(1u << (be >> 5));
        }
    }
    __syncthreads();

    // ---- weights: un-biased score at selected, renormalize * SCALE ----
    {
        const int r = t >> 3, k = t & 7;
        selW[r][k] = sqrtsoftplus(selLf[r][k]);
    }
    __syncthreads();
    if (t < BM) {
        float d = 0.f;
        #pragma unroll
        for (int k = 0; k < K_TOP; ++k) d += selW[t][k];
        invD[t] = SCALE_F / fmaxf(d, 1e-12f);
    }
    __syncthreads();
    {
        const int r = t >> 3, k = t & 7;
        selW[r][k] *= invD[r];
    }
    __syncthreads();

    // ---- dense coalesced output: threads 0..255 probs, 256..511 map ----
    {
        const int e = t & 255;
        const int g = t >> 8;
        for (int r = 0; r < BM; ++r) {
            float w = 0.f, f = 0.f;
            #pragma unroll
            for (int k = 0; k < K_TOP; ++k) {
                if (selE[r][k] == e) { w = selW[r][k]; f = 1.f; }
            }
            const long off = (n0 + r) * (long)E_N + e;
            if (g == 0) probs[off] = w;
            else        rmap[off]  = f;
        }
    }
}

extern "C" void kernel_launch(void* const* d_in, const int* in_sizes, int n_in,
                              void* d_out, int out_size, void* d_ws, size_t ws_size,
                              hipStream_t stream) {
    const float* hidden = (const float*)d_in[0];
    const float* gatew  = (const float*)d_in[1];
    const float* ebias  = (const float*)d_in[2];
    const long E = in_sizes[2];                // 256
    const long D = in_sizes[1] / E;            // 4096
    const long N = in_sizes[0] / D;            // 16384
    float* probs = (float*)d_out;
    float* rmap  = probs + N * E;
    dim3 grid((unsigned)(N / BM));
    router_fused<<<grid, NT, 0, stream>>>(hidden, gatew, ebias, probs, rmap,
                                          (int)N, (int)D);
}

// Round 3
// 987.011 us; speedup vs baseline: 1.1299x; 1.1299x over previous
//
#include <hip/hip_runtime.h>
#include <math.h>
#include <limits.h>

#define E_N   256
#define K_TOP 8
#define BM    64
#define BK    32
#define NT    512
#define SCALE_F 2.5f

#define AS_PITCH (BM + 4)
#define BS_PITCH (E_N + 1)
#define MARGIN_LOGIT 2e-4f   // flag threshold, bias==0 path (keys are logits)
#define MARGIN_SCORE 6e-5f   // flag threshold, biased path (keys are scores)

__device__ __forceinline__ float sqrtsoftplus(float x) {
    const float sp = (x > 20.f) ? x : log1pf(expf(x));
    return sqrtf(sp);
}
__device__ __forceinline__ double sqrtsoftplus_d(double x) {
    const double sp = (x > 30.0) ? x : log1p(exp(x));
    return sqrt(sp);
}

// grid = N/BM blocks (256), NT=512. Block: 64 rows x 256 experts.
// Fast path: fp32 GEMM + top-9. Rows whose 8/9 boundary gap < margin get an
// in-block fp64 recompute + reselect (proved to match the np reference in R2).
__global__ __launch_bounds__(NT, 2) void router_fused(
    const float* __restrict__ hidden,
    const float* __restrict__ gatew,
    const float* __restrict__ ebias,
    float* __restrict__ probs,
    float* __restrict__ rmap,
    int N, int D)
{
    __shared__ union {
        struct { float As[BK][AS_PITCH]; float Bs[BK][BS_PITCH]; } g;   // GEMM stage
        struct { double repLog[E_N]; double pad[832]; float hid[4096]; } r; // repair
    } U;
    __shared__ float biasS[E_N];
    __shared__ int   biasNZ;
    __shared__ int   flagCnt;
    __shared__ int   flagRows[BM];
    __shared__ int   selE[BM][K_TOP];
    __shared__ float selLf[BM][K_TOP];
    __shared__ float selW[BM][K_TOP];
    __shared__ float invD[BM];

    float (*As)[AS_PITCH] = U.g.As;
    float (*Bs)[BS_PITCH] = U.g.Bs;

    const int t  = threadIdx.x;
    const int tx = t & 31;        // expert lane: e = tx + 32*j
    const int ty = t >> 5;        // 0..15 ; rows r0..r0+3
    const int r0 = ty * 4;
    const long n0 = (long)blockIdx.x * BM;

    if (t == 0) { biasNZ = 0; flagCnt = 0; }
    __syncthreads();
    if (t < E_N) {
        const float b = ebias[t];
        biasS[t] = b;
        if (b != 0.f) atomicOr(&biasNZ, 1);
    }

    float acc[4][8];
    #pragma unroll
    for (int i = 0; i < 4; ++i)
        #pragma unroll
        for (int j = 0; j < 8; ++j) acc[i][j] = 0.f;

    // loaders: A: 64 rows x 32 k (1 float4/thread); B: 256 x 32 (4 float4/thread)
    const int lr = t >> 3;            // 0..63
    const int lk = (t & 7) * 4;       // 0,4,...,28
    const float* aP  = hidden + (n0 + lr) * (long)D + lk;
    const float* bP0 = gatew + (long)(lr +   0) * D + lk;
    const float* bP1 = gatew + (long)(lr +  64) * D + lk;
    const float* bP2 = gatew + (long)(lr + 128) * D + lk;
    const float* bP3 = gatew + (long)(lr + 192) * D + lk;

    float4 aReg = *(const float4*)(aP);
    float4 bReg[4];
    bReg[0] = *(const float4*)(bP0);
    bReg[1] = *(const float4*)(bP1);
    bReg[2] = *(const float4*)(bP2);
    bReg[3] = *(const float4*)(bP3);

    for (int k0 = 0; k0 < D; k0 += BK) {
        __syncthreads();
        {   // stage regs -> LDS (transposed: [k][row/expert])
            const float* av = (const float*)&aReg;
            #pragma unroll
            for (int q = 0; q < 4; ++q) As[lk + q][lr] = av[q];
            #pragma unroll
            for (int p = 0; p < 4; ++p) {
                const int e = lr + 64 * p;
                Bs[lk + 0][e] = bReg[p].x;
                Bs[lk + 1][e] = bReg[p].y;
                Bs[lk + 2][e] = bReg[p].z;
                Bs[lk + 3][e] = bReg[p].w;
            }
        }
        __syncthreads();
        const int kn = k0 + BK;
        if (kn < D) {   // prefetch next tile during compute
            aReg    = *(const float4*)(aP  + kn);
            bReg[0] = *(const float4*)(bP0 + kn);
            bReg[1] = *(const float4*)(bP1 + kn);
            bReg[2] = *(const float4*)(bP2 + kn);
            bReg[3] = *(const float4*)(bP3 + kn);
        }
        #pragma unroll 8
        for (int k = 0; k < BK; ++k) {
            const float4 av = *(const float4*)&As[k][r0];
            const float a[4] = {av.x, av.y, av.z, av.w};
            float b[8];
            #pragma unroll
            for (int j = 0; j < 8; ++j) b[j] = Bs[k][tx + 32 * j];
            #pragma unroll
            for (int i = 0; i < 4; ++i)
                #pragma unroll
                for (int j = 0; j < 8; ++j)
                    acc[i][j] = fmaf(a[i], b[j], acc[i][j]);
        }
    }
    __syncthreads();
    const bool bz = (biasNZ == 0);
    const float margin = bz ? MARGIN_LOGIT : MARGIN_SCORE;

    // ---- per-row top-9 via half-wave shuffle; flag near-tie rows ----
    #pragma unroll
    for (int i = 0; i < 4; ++i) {
        const int r = r0 + i;
        float key[8], lf[8];
        #pragma unroll
        for (int j = 0; j < 8; ++j) {
            lf[j] = acc[i][j];
            key[j] = bz ? lf[j] : (sqrtsoftplus(lf[j]) + biasS[tx + 32 * j]);
        }
        unsigned alive = 0xFFu;
        float v8 = 0.f;
        for (int k = 0; k < K_TOP + 1; ++k) {
            float bv = -INFINITY, bf = 0.f; int be = INT_MAX;
            #pragma unroll
            for (int j = 0; j < 8; ++j) {
                if ((alive >> j) & 1u) {
                    if (key[j] > bv) { bv = key[j]; bf = lf[j]; be = tx + 32 * j; }
                }
            }
            #pragma unroll
            for (int m = 16; m >= 1; m >>= 1) {
                const float ov = __shfl_xor(bv, m, 32);
                const float of = __shfl_xor(bf, m, 32);
                const int   oe = __shfl_xor(be, m, 32);
                if (ov > bv || (ov == bv && oe < be)) { bv = ov; bf = of; be = oe; }
            }
            if (k < K_TOP) {
                if (tx == k) { selE[r][k] = be; selLf[r][k] = bf; }
                if ((be & 31) == tx) alive &= ~(1u << (be >> 5));
                if (k == K_TOP - 1) v8 = bv;
            } else if (tx == 0) {
                if (v8 - bv < margin) {
                    const int s = atomicAdd(&flagCnt, 1);
                    flagRows[s] = r;
                }
            }
        }
    }
    __syncthreads();

    // ---- fp64 repair of flagged rows (rare: ~0.25/block expected) ----
    const int nF = flagCnt;
    for (int f = 0; f < nF; ++f) {
        const int row = flagRows[f];
        __syncthreads();   // previous iteration's consumers done with U.r
        {   // stage hidden row into LDS
            const float4* src = (const float4*)(hidden + (n0 + row) * (long)D);
            for (int q = t; q < D / 4; q += NT) ((float4*)U.r.hid)[q] = src[q];
        }
        __syncthreads();
        {   // 8 waves x 32 experts: coalesced fp64 dot + butterfly reduce
            const int w = t >> 6, lane = t & 63;
            for (int j = 0; j < 32; ++j) {
                const int e = w * 32 + j;
                const float4* gp = (const float4*)(gatew + (long)e * D);
                double s0 = 0.0, s1 = 0.0;
                #pragma unroll 4
                for (int i = 0; i < 16; ++i) {
                    const float4 gv = gp[lane + 64 * i];
                    const float4 hv = ((const float4*)U.r.hid)[lane + 64 * i];
                    s0 = fma((double)gv.x, (double)hv.x, s0);
                    s1 = fma((double)gv.y, (double)hv.y, s1);
                    s0 = fma((double)gv.z, (double)hv.z, s0);
                    s1 = fma((double)gv.w, (double)hv.w, s1);
                }
                double s = s0 + s1;
                #pragma unroll
                for (int m = 32; m >= 1; m >>= 1) s += __shfl_xor(s, m, 64);
                if (lane == 0) U.r.repLog[e] = s;
            }
        }
        __syncthreads();
        if (t == 0) {   // serial fp64 top-8 reselect
            double bw[K_TOP]; int bi[K_TOP];
            #pragma unroll
            for (int k = 0; k < K_TOP; ++k) { bw[k] = -(double)INFINITY; bi[k] = -1; }
            for (int e = 0; e < E_N; ++e) {
                const double lg = U.r.repLog[e];
                const double s = bz ? lg : (sqrtsoftplus_d(lg) + (double)biasS[e]);
                if (s > bw[K_TOP - 1]) {
                    int p = K_TOP - 1;
                    while (p > 0 && s > bw[p - 1]) {
                        bw[p] = bw[p - 1]; bi[p] = bi[p - 1]; --p;
                    }
                    bw[p] = s; bi[p] = e;
                }
            }
            #pragma unroll
            for (int k = 0; k < K_TOP; ++k) {
                selE[row][k]  = bi[k];
                selLf[row][k] = (float)U.r.repLog[bi[k]];
            }
        }
    }
    __syncthreads();

    // ---- weights: un-biased score at selected, renormalize * SCALE ----
    {
        const int r = t >> 3, k = t & 7;
        selW[r][k] = sqrtsoftplus(selLf[r][k]);
    }
    __syncthreads();
    if (t < BM) {
        float d = 0.f;
        #pragma unroll
        for (int k = 0; k < K_TOP; ++k) d += selW[t][k];
        invD[t] = SCALE_F / fmaxf(d, 1e-12f);
    }
    __syncthreads();
    {
        const int r = t >> 3, k = t & 7;
        selW[r][k] *= invD[r];
    }
    __syncthreads();

    // ---- dense coalesced output: threads 0..255 probs, 256..511 map ----
    {
        const int e = t & 255;
        const int g = t >> 8;
        for (int r = 0; r < BM; ++r) {
            float w = 0.f, fl = 0.f;
            #pragma unroll
            for (int k = 0; k < K_TOP; ++k) {
                if (selE[r][k] == e) { w = selW[r][k]; fl = 1.f; }
            }
            const long off = (n0 + r) * (long)E_N + e;
            if (g == 0) probs[off] = w;
            else        rmap[off]  = fl;
        }
    }
}

extern "C" void kernel_launch(void* const* d_in, const int* in_sizes, int n_in,
                              void* d_out, int out_size, void* d_ws, size_t ws_size,
                              hipStream_t stream) {
    const float* hidden = (const float*)d_in[0];
    const float* gatew  = (const float*)d_in[1];
    const float* ebias  = (const float*)d_in[2];
    const long E = in_sizes[2];                // 256
    const long D = in_sizes[1] / E;            // 4096
    const long N = in_sizes[0] / D;            // 16384
    float* probs = (float*)d_out;
    float* rmap  = probs + N * E;
    dim3 grid((unsigned)(N / BM));
    router_fused<<<grid, NT, 0, stream>>>(hidden, gatew, ebias, probs, rmap,
                                          (int)N, (int)D);
}

// Round 5
// 702.135 us; speedup vs baseline: 1.5884x; 1.4057x over previous
//
#include <hip/hip_runtime.h>
#include <math.h>
#include <limits.h>

#define E_N   256
#define K_TOP 8
#define BM    64
#define BK    32
#define NT    512
#define SCALE_F 2.5f
#define SPLIT_S   2048.0f        // 2^11: lifts f16 residuals out of denormal range
#define INV_SPLIT (1.0f/2048.0f)
#define MARGIN_LOGIT 2e-4f       // flag threshold, bias==0 path (keys are logits)
#define MARGIN_SCORE 6e-5f       // flag threshold, biased path (keys are scores)
#define PITCH 40                 // f16 row pitch for A/B LDS (80 B: 16B-aligned, 2-way banks = free)

typedef _Float16 half8 __attribute__((ext_vector_type(8)));
typedef _Float16 half4 __attribute__((ext_vector_type(4)));
typedef float    f32x4 __attribute__((ext_vector_type(4)));

__device__ __forceinline__ float sqrtsoftplus(float x) {
    const float sp = (x > 20.f) ? x : log1pf(expf(x));
    return sqrtf(sp);
}
__device__ __forceinline__ double sqrtsoftplus_d(double x) {
    const double sp = (x > 30.0) ? x : log1p(exp(x));
    return sqrt(sp);
}

// grid = N/BM (256) blocks, NT=512 (8 waves). Block: 64 rows x 256 experts.
// GEMM: 3x mfma_f32_16x16x32_f16 per tile (a1b1 -> acc_m; a1b2+a2b1 -> acc_c),
// logit = acc_m + acc_c/2048  (error ~2e-6 << 2e-4 flag margin).
// Selection/top-9/fp64-repair scaffold identical to the R3 kernel (validated).
__global__ __launch_bounds__(NT, 2) void router_fused(
    const float* __restrict__ hidden,
    const float* __restrict__ gatew,
    const float* __restrict__ ebias,
    float* __restrict__ probs,
    float* __restrict__ rmap,
    int N, int D)
{
    __shared__ union {
        struct { _Float16 A[2][BM][PITCH]; _Float16 B[2][E_N][PITCH]; } g; // 51200 B
        float scores[BM][E_N + 1];                                         // 65792 B
        struct { double repLog[E_N]; float hid[4096]; } r;                 // 18432 B
    } U;
    __shared__ float biasS[E_N];
    __shared__ int   biasNZ;
    __shared__ int   flagCnt;
    __shared__ int   flagRows[BM];
    __shared__ int   selE[BM][K_TOP];
    __shared__ float selLf[BM][K_TOP];
    __shared__ float selW[BM][K_TOP];
    __shared__ float invD[BM];

    const int t    = threadIdx.x;
    const int lane = t & 63;
    const int w    = t >> 6;          // wave 0..7 -> experts 32w..32w+31
    const int mrow = lane & 15;       // MFMA frag row/col index
    const int quad = lane >> 4;       // 0..3
    const long n0  = (long)blockIdx.x * BM;

    if (t == 0) { biasNZ = 0; flagCnt = 0; }
    __syncthreads();
    if (t < E_N) {
        const float b = ebias[t];
        biasS[t] = b;
        if (b != 0.f) atomicOr(&biasNZ, 1);
    }

    f32x4 accm[4][2], accc[4][2];
    #pragma unroll
    for (int mt = 0; mt < 4; ++mt)
        #pragma unroll
        for (int nt = 0; nt < 2; ++nt) {
            accm[mt][nt] = (f32x4){0.f, 0.f, 0.f, 0.f};
            accc[mt][nt] = (f32x4){0.f, 0.f, 0.f, 0.f};
        }

    // loaders: A: 64 rows x 32 k (1 float4/thread); B: 256 x 32 (4 float4/thread)
    const int lr = t >> 3;            // 0..63
    const int lk = (t & 7) * 4;       // 0,4,...,28
    const float* aP  = hidden + (n0 + lr) * (long)D + lk;
    const float* bP0 = gatew + (long)(lr +   0) * D + lk;
    const float* bP1 = gatew + (long)(lr +  64) * D + lk;
    const float* bP2 = gatew + (long)(lr + 128) * D + lk;
    const float* bP3 = gatew + (long)(lr + 192) * D + lk;

    float4 aReg = *(const float4*)(aP);
    float4 bReg[4];
    bReg[0] = *(const float4*)(bP0);
    bReg[1] = *(const float4*)(bP1);
    bReg[2] = *(const float4*)(bP2);
    bReg[3] = *(const float4*)(bP3);

    for (int k0 = 0; k0 < D; k0 += BK) {
        __syncthreads();
        {   // convert fp32 -> (hi, lo*2^11) f16 and stage to LDS
            const float* av = (const float*)&aReg;
            half4 hi, lo;
            #pragma unroll
            for (int q = 0; q < 4; ++q) {
                const float f = av[q];
                const _Float16 h = (_Float16)f;
                hi[q] = h;
                lo[q] = (_Float16)((f - (float)h) * SPLIT_S);
            }
            *(half4*)&U.g.A[0][lr][lk] = hi;
            *(half4*)&U.g.A[1][lr][lk] = lo;
            #pragma unroll
            for (int p = 0; p < 4; ++p) {
                const int e = lr + 64 * p;
                const float* bv = (const float*)&bReg[p];
                half4 bhi, blo;
                #pragma unroll
                for (int q = 0; q < 4; ++q) {
                    const float f = bv[q];
                    const _Float16 h = (_Float16)f;
                    bhi[q] = h;
                    blo[q] = (_Float16)((f - (float)h) * SPLIT_S);
                }
                *(half4*)&U.g.B[0][e][lk] = bhi;
                *(half4*)&U.g.B[1][e][lk] = blo;
            }
        }
        __syncthreads();
        const int kn = k0 + BK;
        if (kn < D) {   // prefetch next tile during compute
            aReg    = *(const float4*)(aP  + kn);
            bReg[0] = *(const float4*)(bP0 + kn);
            bReg[1] = *(const float4*)(bP1 + kn);
            bReg[2] = *(const float4*)(bP2 + kn);
            bReg[3] = *(const float4*)(bP3 + kn);
        }
        // fragment reads: A[m=lane&15][k=quad*8+j], B[n=lane&15][k=quad*8+j]
        half8 a1[4], a2[4], b1[2], b2[2];
        #pragma unroll
        for (int mt = 0; mt < 4; ++mt) {
            a1[mt] = *(const half8*)&U.g.A[0][mt * 16 + mrow][quad * 8];
            a2[mt] = *(const half8*)&U.g.A[1][mt * 16 + mrow][quad * 8];
        }
        #pragma unroll
        for (int nt = 0; nt < 2; ++nt) {
            const int e = w * 32 + nt * 16 + mrow;
            b1[nt] = *(const half8*)&U.g.B[0][e][quad * 8];
            b2[nt] = *(const half8*)&U.g.B[1][e][quad * 8];
        }
        #pragma unroll
        for (int mt = 0; mt < 4; ++mt)
            #pragma unroll
            for (int nt = 0; nt < 2; ++nt) {
                accm[mt][nt] = __builtin_amdgcn_mfma_f32_16x16x32_f16(
                    a1[mt], b1[nt], accm[mt][nt], 0, 0, 0);
                accc[mt][nt] = __builtin_amdgcn_mfma_f32_16x16x32_f16(
                    a1[mt], b2[nt], accc[mt][nt], 0, 0, 0);
                accc[mt][nt] = __builtin_amdgcn_mfma_f32_16x16x32_f16(
                    a2[mt], b1[nt], accc[mt][nt], 0, 0, 0);
            }
    }
    __syncthreads();   // staging LDS free; overlay score board

    // C/D layout: row = quad*4 + reg, col = lane&15 -> scores[row][expert]
    #pragma unroll
    for (int mt = 0; mt < 4; ++mt)
        #pragma unroll
        for (int nt = 0; nt < 2; ++nt)
            #pragma unroll
            for (int r = 0; r < 4; ++r) {
                const float lg = accm[mt][nt][r] + accc[mt][nt][r] * INV_SPLIT;
                U.scores[mt * 16 + quad * 4 + r][w * 32 + nt * 16 + mrow] = lg;
            }
    __syncthreads();

    const bool bz = (biasNZ == 0);
    const float margin = bz ? MARGIN_LOGIT : MARGIN_SCORE;
    const int tx = t & 31;
    const int r0 = (t >> 5) * 4;

    // ---- per-row top-9 via half-wave shuffle; flag near-tie rows ----
    #pragma unroll
    for (int i = 0; i < 4; ++i) {
        const int r = r0 + i;
        float key[8], lf[8];
        #pragma unroll
        for (int j = 0; j < 8; ++j) {
            lf[j] = U.scores[r][tx + 32 * j];
            key[j] = bz ? lf[j] : (sqrtsoftplus(lf[j]) + biasS[tx + 32 * j]);
        }
        unsigned alive = 0xFFu;
        float v8 = 0.f;
        for (int k = 0; k < K_TOP + 1; ++k) {
            float bv = -INFINITY, bf = 0.f; int be = INT_MAX;
            #pragma unroll
            for (int j = 0; j < 8; ++j) {
                if ((alive >> j) & 1u) {
                    if (key[j] > bv) { bv = key[j]; bf = lf[j]; be = tx + 32 * j; }
                }
            }
            #pragma unroll
            for (int m = 16; m >= 1; m >>= 1) {
                const float ov = __shfl_xor(bv, m, 32);
                const float of = __shfl_xor(bf, m, 32);
                const int   oe = __shfl_xor(be, m, 32);
                if (ov > bv || (ov == bv && oe < be)) { bv = ov; bf = of; be = oe; }
            }
            if (k < K_TOP) {
                if (tx == k) { selE[r][k] = be; selLf[r][k] = bf; }
                if ((be & 31) == tx) alive &= ~(1u << (be >> 5));
                if (k == K_TOP - 1) v8 = bv;
            } else if (tx == 0) {
                if (v8 - bv < margin) {
                    const int s = atomicAdd(&flagCnt, 1);
                    flagRows[s] = r;
                }
            }
        }
    }
    __syncthreads();

    // ---- fp64 repair of flagged rows (rare; overlays score board) ----
    const int nF = flagCnt;
    for (int f = 0; f < nF; ++f) {
        const int row = flagRows[f];
        __syncthreads();
        {   // stage hidden row into LDS
            const float4* src = (const float4*)(hidden + (n0 + row) * (long)D);
            for (int q = t; q < D / 4; q += NT) ((float4*)U.r.hid)[q] = src[q];
        }
        __syncthreads();
        {   // 8 waves x 32 experts: coalesced fp64 dot + butterfly reduce
            const int lw = t >> 6, ll = t & 63;
            for (int j = 0; j < 32; ++j) {
                const int e = lw * 32 + j;
                const float4* gp = (const float4*)(gatew + (long)e * D);
                double s0 = 0.0, s1 = 0.0;
                #pragma unroll 4
                for (int i = 0; i < 16; ++i) {
                    const float4 gv = gp[ll + 64 * i];
                    const float4 hv = ((const float4*)U.r.hid)[ll + 64 * i];
                    s0 = fma((double)gv.x, (double)hv.x, s0);
                    s1 = fma((double)gv.y, (double)hv.y, s1);
                    s0 = fma((double)gv.z, (double)hv.z, s0);
                    s1 = fma((double)gv.w, (double)hv.w, s1);
                }
                double s = s0 + s1;
                #pragma unroll
                for (int m = 32; m >= 1; m >>= 1) s += __shfl_xor(s, m, 64);
                if (ll == 0) U.r.repLog[e] = s;
            }
        }
        __syncthreads();
        if (t == 0) {   // serial fp64 top-8 reselect
            double bw[K_TOP]; int bi[K_TOP];
            #pragma unroll
            for (int k = 0; k < K_TOP; ++k) { bw[k] = -(double)INFINITY; bi[k] = -1; }
            for (int e = 0; e < E_N; ++e) {
                const double lg = U.r.repLog[e];
                const double s = bz ? lg : (sqrtsoftplus_d(lg) + (double)biasS[e]);
                if (s > bw[K_TOP - 1]) {
                    int p = K_TOP - 1;
                    while (p > 0 && s > bw[p - 1]) {
                        bw[p] = bw[p - 1]; bi[p] = bi[p - 1]; --p;
                    }
                    bw[p] = s; bi[p] = e;
                }
            }
            #pragma unroll
            for (int k = 0; k < K_TOP; ++k) {
                selE[row][k]  = bi[k];
                selLf[row][k] = (float)U.r.repLog[bi[k]];
            }
        }
    }
    __syncthreads();

    // ---- weights: un-biased score at selected, renormalize * SCALE ----
    {
        const int r = t >> 3, k = t & 7;
        selW[r][k] = sqrtsoftplus(selLf[r][k]);
    }
    __syncthreads();
    if (t < BM) {
        float d = 0.f;
        #pragma unroll
        for (int k = 0; k < K_TOP; ++k) d += selW[t][k];
        invD[t] = SCALE_F / fmaxf(d, 1e-12f);
    }
    __syncthreads();
    {
        const int r = t >> 3, k = t & 7;
        selW[r][k] *= invD[r];
    }
    __syncthreads();

    // ---- dense coalesced output: threads 0..255 probs, 256..511 map ----
    {
        const int e = t & 255;
        const int g = t >> 8;
        for (int r = 0; r < BM; ++r) {
            float wv = 0.f, fl = 0.f;
            #pragma unroll
            for (int k = 0; k < K_TOP; ++k) {
                if (selE[r][k] == e) { wv = selW[r][k]; fl = 1.f; }
            }
            const long off = (n0 + r) * (long)E_N + e;
            if (g == 0) probs[off] = wv;
            else        rmap[off]  = fl;
        }
    }
}

extern "C" void kernel_launch(void* const* d_in, const int* in_sizes, int n_in,
                              void* d_out, int out_size, void* d_ws, size_t ws_size,
                              hipStream_t stream) {
    const float* hidden = (const float*)d_in[0];
    const float* gatew  = (const float*)d_in[1];
    const float* ebias  = (const float*)d_in[2];
    const long E = in_sizes[2];                // 256
    const long D = in_sizes[1] / E;            // 4096
    const long N = in_sizes[0] / D;            // 16384
    float* probs = (float*)d_out;
    float* rmap  = probs + N * E;
    dim3 grid((unsigned)(N / BM));
    router_fused<<<grid, NT, 0, stream>>>(hidden, gatew, ebias, probs, rmap,
                                          (int)N, (int)D);
}